// Round 13
// baseline (196.947 us; speedup 1.0000x reference)
//
#include <hip/hip_runtime.h>
#include <hip/hip_bf16.h>

typedef __bf16 bf16x8 __attribute__((ext_vector_type(8)));
typedef __bf16 bf16x4 __attribute__((ext_vector_type(4)));
typedef __bf16 bf16x2 __attribute__((ext_vector_type(2)));
typedef float  f32x4  __attribute__((ext_vector_type(4)));
typedef float  f32x16 __attribute__((ext_vector_type(16)));
typedef unsigned int u32;
typedef u32 u32x2 __attribute__((ext_vector_type(2)));
typedef u32 u32x4 __attribute__((ext_vector_type(4)));

#define S_  2048
#define E_  1024
#define NH_ 64

__device__ __forceinline__ f32x4 mfma16(bf16x8 a, bf16x8 b, f32x4 c) {
    return __builtin_amdgcn_mfma_f32_16x16x32_bf16(a, b, c, 0, 0, 0);
}
__device__ __forceinline__ f32x16 mfma32(bf16x8 a, bf16x8 b, f32x16 c) {
    return __builtin_amdgcn_mfma_f32_32x32x16_bf16(a, b, c, 0, 0, 0);
}
__device__ __forceinline__ u32 pack2(float a, float b) {
    bf16x2 t; t[0] = (__bf16)a; t[1] = (__bf16)b;
    return __builtin_bit_cast(u32, t);
}
__device__ __forceinline__ void swap32(u32& a, u32& b) {
    asm("v_permlane32_swap_b32 %0, %1" : "+v"(a), "+v"(b));
}
__device__ __forceinline__ f32x16 zero16() {
    f32x16 z;
#pragma unroll
    for (int i = 0; i < 16; ++i) z[i] = 0.f;
    return z;
}
__device__ __forceinline__ void gload_lds16(const void* g, void* l) {
    __builtin_amdgcn_global_load_lds(
        (const __attribute__((address_space(1))) unsigned int*)g,
        (__attribute__((address_space(3))) unsigned int*)l, 16, 0, 0);
}

// ------------------------------------------------- QKV per-head projections
// z=0 V: Vt[nh][d][s]           (transposed, PLAIN - k_attn reads V direct)
// z=1 K: Kws[nh][s][e ^ ((s&7)<<3)]  (16B swizzle for k_attn's b128 LDS reads)
// z=2 Q: Qws[nh][s][e] plain; log2(e)/32 folded into Wq.
// z=3:   Wo fp32 -> Wob bf16 pre-swizzled (for k_out)    [merged k_cast]
// W fragments loaded once per block; 4 x 64-row iterations; LDS-tile copyout.
#define TP 72   // padded LDS row stride (elems)
__global__ __launch_bounds__(256) void k_proj(const float* __restrict__ vin,
                                              const float* __restrict__ kin,
                                              const float* __restrict__ qin,
                                              const float* __restrict__ Wv,
                                              const float* __restrict__ Wk,
                                              const float* __restrict__ Wq,
                                              const float* __restrict__ Wo,
                                              __bf16* __restrict__ Qws,
                                              __bf16* __restrict__ Kws,
                                              __bf16* __restrict__ Vt,
                                              __bf16* __restrict__ Wob) {
    __shared__ __align__(16) __bf16 tile[64 * TP];   // 9 KB
    const int z = blockIdx.z;
    if (z == 3) {   // Wo cast (block-uniform branch)
        int i = (blockIdx.x * 256 + threadIdx.x) * 8;
        int o = i >> 10, e0 = i & 1023;
        float4 a = *(const float4*)(Wo + i);
        float4 b = *(const float4*)(Wo + i + 4);
        bf16x8 f;
        f[0] = (__bf16)a.x; f[1] = (__bf16)a.y; f[2] = (__bf16)a.z; f[3] = (__bf16)a.w;
        f[4] = (__bf16)b.x; f[5] = (__bf16)b.y; f[6] = (__bf16)b.z; f[7] = (__bf16)b.w;
        int e_swz = (e0 & ~63) | ((e0 & 63) ^ ((o & 7) << 3));
        *(bf16x8*)(Wob + (size_t)o * 1024 + e_swz) = f;
        return;
    }
    const float* in = (z == 0) ? vin : ((z == 1) ? kin : qin);
    const float* W  = (z == 0) ? Wv  : ((z == 1) ? Wk  : Wq);
    const float scale = (z == 2) ? 0.04508422f : 1.0f;  // log2(e)/32
    const int bid  = blockIdx.x;                 // 512 blocks: 64 nh x 8 groups
    const int nh   = bid >> 3;
    const int sbase = (bid & 7) << 8;            // 256 rows per block
    const int n = nh >> 4, h = nh & 15;
    const int lane = threadIdx.x & 63, wid = threadIdx.x >> 6;
    const int l16 = lane & 15, g = lane >> 4;

    // W fragments: loop-invariant, loaded once per block
    bf16x8 Bf[4][2];
#pragma unroll
    for (int nt = 0; nt < 4; ++nt)
#pragma unroll
        for (int ks = 0; ks < 2; ++ks) {
            const float* wp = W + (nt * 16 + l16) * 64 + ks * 32 + g * 8;
            float4 a = *(const float4*)wp;
            float4 b = *(const float4*)(wp + 4);
            bf16x8 f;
            f[0] = (__bf16)(a.x * scale); f[1] = (__bf16)(a.y * scale);
            f[2] = (__bf16)(a.z * scale); f[3] = (__bf16)(a.w * scale);
            f[4] = (__bf16)(b.x * scale); f[5] = (__bf16)(b.y * scale);
            f[6] = (__bf16)(b.z * scale); f[7] = (__bf16)(b.w * scale);
            Bf[nt][ks] = f;
        }

    for (int it = 0; it < 4; ++it) {
        const int sblk = sbase + it * 64;
        const int s = sblk + wid * 16 + l16;
        const float* ip = in + ((size_t)n * S_ + s) * E_ + h * 64 + g * 8;
        bf16x8 Af[2];
#pragma unroll
        for (int ks = 0; ks < 2; ++ks) {
            float4 a = *(const float4*)(ip + ks * 32);
            float4 b = *(const float4*)(ip + ks * 32 + 4);
            bf16x8 f;
            f[0] = (__bf16)a.x; f[1] = (__bf16)a.y; f[2] = (__bf16)a.z; f[3] = (__bf16)a.w;
            f[4] = (__bf16)b.x; f[5] = (__bf16)b.y; f[6] = (__bf16)b.z; f[7] = (__bf16)b.w;
            Af[ks] = f;
        }

        f32x4 acc[4];
#pragma unroll
        for (int nt = 0; nt < 4; ++nt) { acc[nt][0] = 0.f; acc[nt][1] = 0.f; acc[nt][2] = 0.f; acc[nt][3] = 0.f; }

        if (it > 0) __syncthreads();   // tile free from previous copyout
        if (z == 0) {
            // non-swapped: lane dim = d, reg dim = s-run of 4; PLAIN layout
#pragma unroll
            for (int nt = 0; nt < 4; ++nt) {
                acc[nt] = mfma16(Af[0], Bf[nt][0], acc[nt]);
                acc[nt] = mfma16(Af[1], Bf[nt][1], acc[nt]);
            }
#pragma unroll
            for (int nt = 0; nt < 4; ++nt) {
                int d = nt * 16 + l16;
                int scol = wid * 16 + g * 4;
                bf16x4 o;
#pragma unroll
                for (int r = 0; r < 4; ++r) o[r] = (__bf16)acc[nt][r];
                *(bf16x4*)(tile + d * TP + scol) = o;   // row = d
            }
        } else {
            // swapped: lane dim = s, reg dim = e-run of 4
#pragma unroll
            for (int nt = 0; nt < 4; ++nt) {
                acc[nt] = mfma16(Bf[nt][0], Af[0], acc[nt]);
                acc[nt] = mfma16(Bf[nt][1], Af[1], acc[nt]);
            }
            const int sl = wid * 16 + l16;
            const int fk = (z == 1) ? ((sl & 7) << 3) : 0;
#pragma unroll
            for (int nt = 0; nt < 4; ++nt) {
                int e0 = (nt * 16 + g * 4) ^ fk;
                bf16x4 o;
#pragma unroll
                for (int r = 0; r < 4; ++r) o[r] = (__bf16)acc[nt][r];
                *(bf16x4*)(tile + sl * TP + e0) = o;    // row = s-local
            }
        }
        __syncthreads();

        // copy out row-linear: thread t -> row t>>2, 32B chunk (t&3)
        const int trow = threadIdx.x >> 2, tc = (threadIdx.x & 3) * 16;
        bf16x8 v0 = *(const bf16x8*)(tile + trow * TP + tc);
        bf16x8 v1 = *(const bf16x8*)(tile + trow * TP + tc + 8);
        __bf16* dst;
        if (z == 0)      dst = Vt  + ((size_t)nh * 64 + trow) * S_ + sblk + tc;
        else if (z == 1) dst = Kws + ((size_t)nh * S_ + sblk + trow) * 64 + tc;
        else             dst = Qws + ((size_t)nh * S_ + sblk + trow) * 64 + tc;
        *(bf16x8*)dst = v0;
        *(bf16x8*)(dst + 8) = v1;
    }
}

// ----------------------------------------------------------- flash attention
// r5 structure (4 waves x 32 q, grid 1024, lb(256,4), K via LDS w/ b128+16B
// swizzle) but V read DIRECTLY from global (L2-resident: 256KB/head, 2MB/XCD)
// -> LDS read traffic halved, staging halved, V on the idle VMEM pipe.
// V loads issue right after the barrier, BEFORE next-tile stage (vmcnt order).
__global__ __launch_bounds__(256, 4) void k_attn(const __bf16* __restrict__ Qws,
                                                 const __bf16* __restrict__ Kws,
                                                 const __bf16* __restrict__ Vt,
                                                 const int* __restrict__ maskp,
                                                 __bf16* __restrict__ Xws) {
    __shared__ __align__(16) char lds[2][8192];  // [buf][K 8KB]
    const int tid = threadIdx.x, lane = tid & 63, wid = tid >> 6;
    const int l31 = lane & 31, hf = lane >> 5, h8 = hf * 8;
    // XCD swizzle: 1024 blocks = 8 xcd x (8 nh x 16 qb); XCD x -> nh [8x,8x+8)
    const int v = blockIdx.x;
    const int u = v >> 3;
    const int nh = (v & 7) * 8 + (u & 7), qb = u >> 3;
    const int n = nh >> 4, hd = nh & 15;

    int az = 0;
    for (int i = tid; i < S_; i += 256) az |= (maskp[(size_t)n * S_ + i] == 0);
    const int anyzero = __syncthreads_or(az);

    const char* Kc = (const char*)(Kws + (size_t)nh * S_ * 64);
    const __bf16* Vg = Vt + (size_t)nh * 64 * S_;
    const __bf16* Qb = Qws + (size_t)nh * S_ * 64;

    const int q0 = qb * 128 + wid * 32;
    bf16x8 Qf[4];
#pragma unroll
    for (int dt = 0; dt < 4; ++dt)
        Qf[dt] = *(const bf16x8*)(Qb + (size_t)(q0 + l31) * 64 + dt * 16 + h8);

    f32x16 acc0 = zero16(), acc1 = zero16();
    float lsum = 0.f;

    // stage one 8KB K tile: 2 x gload_lds16 per thread
    auto stage = [&](int buf, int kb) {
        char* base = &lds[buf][0];
        const char* ks = Kc + (size_t)kb * 8192 + wid * 2048 + lane * 16;
        char* kd = base + wid * 2048;
        gload_lds16(ks, kd);
        gload_lds16(ks + 1024, kd + 1024);
    };

    const int swz = (l31 & 7) << 4;
    const __bf16* Vr0 = Vg + (size_t)l31 * S_ + h8;        // d rows 0-31
    const __bf16* Vr1 = Vg + (size_t)(32 + l31) * S_ + h8; // d rows 32-63

    stage(0, 0);
    int buf = 0;
    for (int kb = 0; kb < 32; ++kb) {
        __syncthreads();
        // V fragments for tile kb, direct from global (oldest VMEM ops)
        const int vc = kb * 64;
        bf16x8 V000 = *(const bf16x8*)(Vr0 + vc);        // kt0 s0 t0
        bf16x8 V001 = *(const bf16x8*)(Vr1 + vc);        // kt0 s0 t1
        bf16x8 V010 = *(const bf16x8*)(Vr0 + vc + 16);   // kt0 s1 t0
        bf16x8 V011 = *(const bf16x8*)(Vr1 + vc + 16);   // kt0 s1 t1
        bf16x8 V100 = *(const bf16x8*)(Vr0 + vc + 32);   // kt1 s0 t0
        bf16x8 V101 = *(const bf16x8*)(Vr1 + vc + 32);   // kt1 s0 t1
        bf16x8 V110 = *(const bf16x8*)(Vr0 + vc + 48);   // kt1 s1 t0
        bf16x8 V111 = *(const bf16x8*)(Vr1 + vc + 48);   // kt1 s1 t1
        if (kb < 31) stage(buf ^ 1, kb + 1);             // younger than V loads
        char* base = &lds[buf][0];
        const int k0 = kb * 64;

        auto ktbody = [&](int kt, bf16x8 Vs0t0, bf16x8 Vs0t1, bf16x8 Vs1t0, bf16x8 Vs1t1) {
            bf16x8 K0 = *(const bf16x8*)(base + (kt * 32 + l31) * 128 + (((0 * 2 + hf) * 16) ^ swz));
            bf16x8 K1 = *(const bf16x8*)(base + (kt * 32 + l31) * 128 + (((1 * 2 + hf) * 16) ^ swz));
            bf16x8 K2 = *(const bf16x8*)(base + (kt * 32 + l31) * 128 + (((2 * 2 + hf) * 16) ^ swz));
            bf16x8 K3 = *(const bf16x8*)(base + (kt * 32 + l31) * 128 + (((3 * 2 + hf) * 16) ^ swz));
            __builtin_amdgcn_s_setprio(1);
            f32x16 sA = zero16();
            sA = mfma32(K0, Qf[0], sA); sA = mfma32(K1, Qf[1], sA);
            sA = mfma32(K2, Qf[2], sA); sA = mfma32(K3, Qf[3], sA);
            __builtin_amdgcn_s_setprio(0);
            if (anyzero) {
#pragma unroll
                for (int r = 0; r < 16; ++r) {
                    int kk = k0 + kt * 32 + (r & 3) + 8 * (r >> 2) + 4 * hf;
                    if (maskp[(size_t)n * S_ + kk] == 0) sA[r] = -1e30f;
                }
            }
            float p[16];
#pragma unroll
            for (int r = 0; r < 16; ++r) p[r] = __builtin_amdgcn_exp2f(sA[r]);
            lsum += ((((p[0] + p[1]) + (p[2] + p[3])) + ((p[4] + p[5]) + (p[6] + p[7])))
                  + (((p[8] + p[9]) + (p[10] + p[11])) + ((p[12] + p[13]) + (p[14] + p[15]))));
            u32 w0 = pack2(p[0],  p[1]),  w1 = pack2(p[2],  p[3]);
            u32 w2 = pack2(p[4],  p[5]),  w3 = pack2(p[6],  p[7]);
            u32 w4 = pack2(p[8],  p[9]),  w5 = pack2(p[10], p[11]);
            u32 w6 = pack2(p[12], p[13]), w7 = pack2(p[14], p[15]);
            swap32(w0, w2); swap32(w1, w3); swap32(w4, w6); swap32(w5, w7);
            u32x4 t0; t0[0] = w0; t0[1] = w1; t0[2] = w2; t0[3] = w3;
            u32x4 t1; t1[0] = w4; t1[1] = w5; t1[2] = w6; t1[3] = w7;
            bf16x8 P0 = __builtin_bit_cast(bf16x8, t0);
            bf16x8 P1 = __builtin_bit_cast(bf16x8, t1);
            __builtin_amdgcn_s_setprio(1);
            acc0 = mfma32(Vs0t0, P0, acc0); acc0 = mfma32(Vs1t0, P1, acc0);
            acc1 = mfma32(Vs0t1, P0, acc1); acc1 = mfma32(Vs1t1, P1, acc1);
            __builtin_amdgcn_s_setprio(0);
        };
        ktbody(0, V000, V001, V010, V011);
        ktbody(1, V100, V101, V110, V111);
        buf ^= 1;
    }

    lsum += __shfl_xor(lsum, 32);
    const float inv = 1.0f / lsum;
    const int qg = q0 + l31;
    __bf16* Ob = Xws + ((size_t)(n * S_ + qg)) * E_ + hd * 64;
    const int qsw = (qg & 7) << 3;

    auto store_half = [&](const f32x16& a, int dv) {
#pragma unroll
        for (int rr = 0; rr < 4; ++rr) {
            bf16x4 o;
#pragma unroll
            for (int j = 0; j < 4; ++j) o[j] = (__bf16)(a[rr * 4 + j] * inv);
            int dsw = ((dv * 32 + rr * 8) ^ qsw) + hf * 4;  // pre-swizzle for k_out
            *(bf16x4*)(Ob + dsw) = o;
        }
    };
    store_half(acc0, 0);
    store_half(acc1, 1);
}

// ------------------------------------------------------- output GEMM + bias
// 128x128 block tile, BK=64, LDS-staged (global_load_lds, double-buffered),
// swizzled ds_read_b128 (swizzle pre-applied in global X / Wob).
__global__ __launch_bounds__(256) void k_out(const __bf16* __restrict__ Xws,
                                             const __bf16* __restrict__ Wob,
                                             const float* __restrict__ bo,
                                             float* __restrict__ out) {
    __shared__ __align__(16) char Al[2][16384];
    __shared__ __align__(16) char Bl[2][16384];
    const int tid = threadIdx.x, lane = tid & 63, wid = tid >> 6;
    const int l31 = lane & 31, hf = lane >> 5;
    const int v = blockIdx.x;
    const int id2 = (v & 7) * 64 + (v >> 3);
    const int mb = id2 >> 3, ob = id2 & 7;
    const int m0 = mb * 128, o0 = ob * 128;
    const int wr = wid >> 1, wc = wid & 1;

    const char* Xb = (const char*)Xws + (size_t)m0 * 2048;
    const char* Wb = (const char*)Wob + (size_t)o0 * 2048;
    const int r = tid >> 3, cb = (tid & 7) * 16;

    auto stage = [&](int buf, int kb) {
#pragma unroll
        for (int p = 0; p < 4; ++p) {
            gload_lds16(Xb + (size_t)(p * 32 + r) * 2048 + kb * 128 + cb,
                        &Al[buf][p * 4096 + wid * 1024]);
            gload_lds16(Wb + (size_t)(p * 32 + r) * 2048 + kb * 128 + cb,
                        &Bl[buf][p * 4096 + wid * 1024]);
        }
    };

    f32x16 acc00 = zero16(), acc01 = zero16(), acc10 = zero16(), acc11 = zero16();

    const int arow0 = (wr * 64 + l31) * 128;
    const int brow0 = (wc * 64 + l31) * 128;
    const int rsw = (l31 & 7) << 4;

    stage(0, 0);
    int buf = 0;
    for (int kb = 0; kb < 16; ++kb) {
        __syncthreads();
        if (kb < 15) stage(buf ^ 1, kb + 1);
        const char* ab = &Al[buf][0];
        const char* bb = &Bl[buf][0];
#pragma unroll
        for (int ks = 0; ks < 4; ++ks) {
            const int co = (ks * 32 + hf * 16) ^ rsw;
            bf16x8 A0 = *(const bf16x8*)(ab + arow0 + co);
            bf16x8 A1 = *(const bf16x8*)(ab + arow0 + 32 * 128 + co);
            bf16x8 B0 = *(const bf16x8*)(bb + brow0 + co);
            bf16x8 B1 = *(const bf16x8*)(bb + brow0 + 32 * 128 + co);
            __builtin_amdgcn_s_setprio(1);
            acc00 = mfma32(A0, B0, acc00);
            acc01 = mfma32(A0, B1, acc01);
            acc10 = mfma32(A1, B0, acc10);
            acc11 = mfma32(A1, B1, acc11);
            __builtin_amdgcn_s_setprio(0);
        }
        buf ^= 1;
    }

    const float bias0 = bo[o0 + wc * 64 + l31];
    const float bias1 = bo[o0 + wc * 64 + 32 + l31];
#pragma unroll
    for (int sm = 0; sm < 2; ++sm) {
        const f32x16& a0 = (sm == 0) ? acc00 : acc10;
        const f32x16& a1 = (sm == 0) ? acc01 : acc11;
#pragma unroll
        for (int rr = 0; rr < 4; ++rr)
#pragma unroll
            for (int j = 0; j < 4; ++j) {
                size_t m = (size_t)m0 + wr * 64 + sm * 32 + rr * 8 + hf * 4 + j;
                out[m * E_ + o0 + wc * 64 + l31]      = a0[rr * 4 + j] + bias0;
                out[m * E_ + o0 + wc * 64 + 32 + l31] = a1[rr * 4 + j] + bias1;
            }
    }
}

extern "C" void kernel_launch(void* const* d_in, const int* in_sizes, int n_in,
                              void* d_out, int out_size, void* d_ws, size_t ws_size,
                              hipStream_t stream) {
    const float* vin  = (const float*)d_in[0];
    const float* kin  = (const float*)d_in[1];
    const float* qin  = (const float*)d_in[2];
    const int*   mask = (const int*)d_in[3];
    const float* Wv   = (const float*)d_in[4];
    const float* Wk   = (const float*)d_in[5];
    const float* Wq   = (const float*)d_in[6];
    const float* Wo   = (const float*)d_in[7];
    const float* bo   = (const float*)d_in[8];

    __bf16* Qws = (__bf16*)d_ws;                       // [64][2048][64]
    __bf16* Kws = Qws + (size_t)NH_ * S_ * 64;         // [64][2048][64] swizzled
    __bf16* Vt  = Kws + (size_t)NH_ * S_ * 64;         // [64][64][2048] plain
    __bf16* Xws = Vt  + (size_t)NH_ * S_ * 64;         // [4][2048][1024] swizzled
    __bf16* Wob = Xws + (size_t)4 * S_ * E_;           // [1024][1024] swizzled
    float* out = (float*)d_out;

    hipLaunchKernelGGL(k_proj, dim3(512, 1, 4), dim3(256), 0, stream,
                       vin, kin, qin, Wv, Wk, Wq, Wo, Qws, Kws, Vt, Wob);
    hipLaunchKernelGGL(k_attn, dim3(1024), dim3(256), 0, stream, Qws, Kws, Vt, mask, Xws);
    hipLaunchKernelGGL(k_out, dim3(512), dim3(256), 0, stream, Xws, Wob, bo, out);
}

// Round 14
// 136.707 us; speedup vs baseline: 1.4406x; 1.4406x over previous
//
#include <hip/hip_runtime.h>
#include <hip/hip_bf16.h>

typedef __bf16 bf16x8 __attribute__((ext_vector_type(8)));
typedef __bf16 bf16x4 __attribute__((ext_vector_type(4)));
typedef __bf16 bf16x2 __attribute__((ext_vector_type(2)));
typedef float  f32x4  __attribute__((ext_vector_type(4)));
typedef float  f32x16 __attribute__((ext_vector_type(16)));
typedef unsigned int u32;
typedef u32 u32x2 __attribute__((ext_vector_type(2)));
typedef u32 u32x4 __attribute__((ext_vector_type(4)));

#define S_  2048
#define E_  1024
#define NH_ 64

__device__ __forceinline__ f32x4 mfma16(bf16x8 a, bf16x8 b, f32x4 c) {
    return __builtin_amdgcn_mfma_f32_16x16x32_bf16(a, b, c, 0, 0, 0);
}
__device__ __forceinline__ f32x16 mfma32(bf16x8 a, bf16x8 b, f32x16 c) {
    return __builtin_amdgcn_mfma_f32_32x32x16_bf16(a, b, c, 0, 0, 0);
}
__device__ __forceinline__ u32 pack2(float a, float b) {
    bf16x2 t; t[0] = (__bf16)a; t[1] = (__bf16)b;
    return __builtin_bit_cast(u32, t);
}
__device__ __forceinline__ void swap32(u32& a, u32& b) {
    asm("v_permlane32_swap_b32 %0, %1" : "+v"(a), "+v"(b));
}
__device__ __forceinline__ f32x16 zero16() {
    f32x16 z;
#pragma unroll
    for (int i = 0; i < 16; ++i) z[i] = 0.f;
    return z;
}
__device__ __forceinline__ void gload_lds16(const void* g, void* l) {
    __builtin_amdgcn_global_load_lds(
        (const __attribute__((address_space(1))) unsigned int*)g,
        (__attribute__((address_space(3))) unsigned int*)l, 16, 0, 0);
}

// ------------------------------------------------- QKV per-head projections
// z=0 V: Vt[nh][d][s ^ ((d&7)<<3)]   (transposed, 16B swizzle for b128 reads)
// z=1 K: Kws[nh][s][e ^ ((s&7)<<3)]
// z=2 Q: Qws[nh][s][e] plain; log2(e)/32 folded into Wq.
// z=3:   Wo fp32 -> Wob bf16 pre-swizzled (for k_out)
// W fragments loaded once per block; 4 x 64-row iterations; LDS-tile copyout.
#define TP 72   // padded LDS row stride (elems)
__global__ __launch_bounds__(256) void k_proj(const float* __restrict__ vin,
                                              const float* __restrict__ kin,
                                              const float* __restrict__ qin,
                                              const float* __restrict__ Wv,
                                              const float* __restrict__ Wk,
                                              const float* __restrict__ Wq,
                                              const float* __restrict__ Wo,
                                              __bf16* __restrict__ Qws,
                                              __bf16* __restrict__ Kws,
                                              __bf16* __restrict__ Vt,
                                              __bf16* __restrict__ Wob) {
    __shared__ __align__(16) __bf16 tile[64 * TP];   // 9 KB
    const int z = blockIdx.z;
    if (z == 3) {   // Wo cast (block-uniform branch)
        int i = (blockIdx.x * 256 + threadIdx.x) * 8;
        int o = i >> 10, e0 = i & 1023;
        float4 a = *(const float4*)(Wo + i);
        float4 b = *(const float4*)(Wo + i + 4);
        bf16x8 f;
        f[0] = (__bf16)a.x; f[1] = (__bf16)a.y; f[2] = (__bf16)a.z; f[3] = (__bf16)a.w;
        f[4] = (__bf16)b.x; f[5] = (__bf16)b.y; f[6] = (__bf16)b.z; f[7] = (__bf16)b.w;
        int e_swz = (e0 & ~63) | ((e0 & 63) ^ ((o & 7) << 3));
        *(bf16x8*)(Wob + (size_t)o * 1024 + e_swz) = f;
        return;
    }
    const float* in = (z == 0) ? vin : ((z == 1) ? kin : qin);
    const float* W  = (z == 0) ? Wv  : ((z == 1) ? Wk  : Wq);
    const float scale = (z == 2) ? 0.04508422f : 1.0f;  // log2(e)/32
    const int bid  = blockIdx.x;                 // 512 blocks: 64 nh x 8 groups
    const int nh   = bid >> 3;
    const int sbase = (bid & 7) << 8;            // 256 rows per block
    const int n = nh >> 4, h = nh & 15;
    const int lane = threadIdx.x & 63, wid = threadIdx.x >> 6;
    const int l16 = lane & 15, g = lane >> 4;

    // W fragments: loop-invariant, loaded once per block
    bf16x8 Bf[4][2];
#pragma unroll
    for (int nt = 0; nt < 4; ++nt)
#pragma unroll
        for (int ks = 0; ks < 2; ++ks) {
            const float* wp = W + (nt * 16 + l16) * 64 + ks * 32 + g * 8;
            float4 a = *(const float4*)wp;
            float4 b = *(const float4*)(wp + 4);
            bf16x8 f;
            f[0] = (__bf16)(a.x * scale); f[1] = (__bf16)(a.y * scale);
            f[2] = (__bf16)(a.z * scale); f[3] = (__bf16)(a.w * scale);
            f[4] = (__bf16)(b.x * scale); f[5] = (__bf16)(b.y * scale);
            f[6] = (__bf16)(b.z * scale); f[7] = (__bf16)(b.w * scale);
            Bf[nt][ks] = f;
        }

    for (int it = 0; it < 4; ++it) {
        const int sblk = sbase + it * 64;
        const int s = sblk + wid * 16 + l16;
        const float* ip = in + ((size_t)n * S_ + s) * E_ + h * 64 + g * 8;
        bf16x8 Af[2];
#pragma unroll
        for (int ks = 0; ks < 2; ++ks) {
            float4 a = *(const float4*)(ip + ks * 32);
            float4 b = *(const float4*)(ip + ks * 32 + 4);
            bf16x8 f;
            f[0] = (__bf16)a.x; f[1] = (__bf16)a.y; f[2] = (__bf16)a.z; f[3] = (__bf16)a.w;
            f[4] = (__bf16)b.x; f[5] = (__bf16)b.y; f[6] = (__bf16)b.z; f[7] = (__bf16)b.w;
            Af[ks] = f;
        }

        f32x4 acc[4];
#pragma unroll
        for (int nt = 0; nt < 4; ++nt) { acc[nt][0] = 0.f; acc[nt][1] = 0.f; acc[nt][2] = 0.f; acc[nt][3] = 0.f; }

        if (it > 0) __syncthreads();   // tile free from previous copyout
        if (z == 0) {
            // non-swapped: lane dim = d, reg dim = s-run of 4
#pragma unroll
            for (int nt = 0; nt < 4; ++nt) {
                acc[nt] = mfma16(Af[0], Bf[nt][0], acc[nt]);
                acc[nt] = mfma16(Af[1], Bf[nt][1], acc[nt]);
            }
#pragma unroll
            for (int nt = 0; nt < 4; ++nt) {
                int d = nt * 16 + l16;
                int scol = (wid * 16 + g * 4) ^ ((d & 7) << 3);
                bf16x4 o;
#pragma unroll
                for (int r = 0; r < 4; ++r) o[r] = (__bf16)acc[nt][r];
                *(bf16x4*)(tile + d * TP + scol) = o;   // row = d
            }
        } else {
            // swapped: lane dim = s, reg dim = e-run of 4
#pragma unroll
            for (int nt = 0; nt < 4; ++nt) {
                acc[nt] = mfma16(Bf[nt][0], Af[0], acc[nt]);
                acc[nt] = mfma16(Bf[nt][1], Af[1], acc[nt]);
            }
            const int sl = wid * 16 + l16;
            const int fk = (z == 1) ? ((sl & 7) << 3) : 0;
#pragma unroll
            for (int nt = 0; nt < 4; ++nt) {
                int e0 = (nt * 16 + g * 4) ^ fk;
                bf16x4 o;
#pragma unroll
                for (int r = 0; r < 4; ++r) o[r] = (__bf16)acc[nt][r];
                *(bf16x4*)(tile + sl * TP + e0) = o;    // row = s-local
            }
        }
        __syncthreads();

        // copy out row-linear: thread t -> row t>>2, 32B chunk (t&3)
        const int trow = threadIdx.x >> 2, tc = (threadIdx.x & 3) * 16;
        bf16x8 v0 = *(const bf16x8*)(tile + trow * TP + tc);
        bf16x8 v1 = *(const bf16x8*)(tile + trow * TP + tc + 8);
        __bf16* dst;
        if (z == 0)      dst = Vt  + ((size_t)nh * 64 + trow) * S_ + sblk + tc;
        else if (z == 1) dst = Kws + ((size_t)nh * S_ + sblk + trow) * 64 + tc;
        else             dst = Qws + ((size_t)nh * S_ + sblk + trow) * 64 + tc;
        *(bf16x8*)dst = v0;
        *(bf16x8*)(dst + 8) = v1;
    }
}

// ----------------------------------------------------------- flash attention
// r12-verbatim structure (verified 87us k_attn): 4 waves x 32 q, grid 1024,
// lb(256,4), K+V staged via global_load_lds (double-buffered, b128 reads with
// 16B XOR swizzle pre-applied in global), in-register softmax.
// CHANGE vs r12: startup de-serialized — stage(0,0) + Q loads issue first;
// mask scan is per-wave (int4 + __any), no initial block barrier.
__global__ __launch_bounds__(256, 4) void k_attn(const __bf16* __restrict__ Qws,
                                                 const __bf16* __restrict__ Kws,
                                                 const __bf16* __restrict__ Vt,
                                                 const int* __restrict__ maskp,
                                                 __bf16* __restrict__ Xws) {
    __shared__ __align__(16) char lds[2][16384];  // [buf][K 8KB | V 8KB]
    const int tid = threadIdx.x, lane = tid & 63, wid = tid >> 6;
    const int l31 = lane & 31, hf = lane >> 5, h8 = hf * 8;
    // XCD swizzle: 1024 blocks = 8 xcd x (8 nh x 16 qb); XCD x -> nh [8x,8x+8)
    const int v = blockIdx.x;
    const int u = v >> 3;
    const int nh = (v & 7) * 8 + (u & 7), qb = u >> 3;
    const int n = nh >> 4, hd = nh & 15;

    const char* Kc = (const char*)(Kws + (size_t)nh * S_ * 64);
    const char* Vc = (const char*)(Vt  + (size_t)nh * 64 * S_);
    const __bf16* Qb = Qws + (size_t)nh * S_ * 64;

    // stage 16KB with 256 threads: 4 x gload_lds16 per thread
    auto stage = [&](int buf, int kb) {
        char* base = &lds[buf][0];
        const char* ks = Kc + (size_t)kb * 8192 + wid * 2048 + lane * 16;
        char* kd = base + wid * 2048;
        gload_lds16(ks, kd);
        gload_lds16(ks + 1024, kd + 1024);
        const int r0 = wid * 16 + (lane >> 3);
        const char* vs = Vc + (size_t)r0 * (S_ * 2) + (size_t)kb * 128 + (lane & 7) * 16;
        char* vd = base + 8192 + wid * 2048;
        gload_lds16(vs, vd);
        gload_lds16(vs + (size_t)8 * (S_ * 2), vd + 1024);
    };

    stage(0, 0);   // first tile in flight before anything else

    const int q0 = qb * 128 + wid * 32;
    bf16x8 Qf[4];
#pragma unroll
    for (int dt = 0; dt < 4; ++dt)
        Qf[dt] = *(const bf16x8*)(Qb + (size_t)(q0 + l31) * 64 + dt * 16 + h8);

    // per-wave mask scan: 8 x int4 per lane covers 2048 ints; no block barrier
    const int4* mp = (const int4*)(maskp + (size_t)n * S_);
    int az = 0;
#pragma unroll
    for (int i = 0; i < 8; ++i) {
        int4 m4 = mp[lane + i * 64];
        az |= (m4.x == 0) | (m4.y == 0) | (m4.z == 0) | (m4.w == 0);
    }
    const int anyzero = __any(az);

    f32x16 acc0 = zero16(), acc1 = zero16();
    float lsum = 0.f;

    const int swz = (l31 & 7) << 4;

    int buf = 0;
    for (int kb = 0; kb < 32; ++kb) {
        __syncthreads();
        if (kb < 31) stage(buf ^ 1, kb + 1);
        char* base = &lds[buf][0];
        char* vbase = base + 8192;
        const int k0 = kb * 64;
#pragma unroll
        for (int kt = 0; kt < 2; ++kt) {
            bf16x8 K0 = *(const bf16x8*)(base + (kt * 32 + l31) * 128 + (((0 * 2 + hf) * 16) ^ swz));
            bf16x8 K1 = *(const bf16x8*)(base + (kt * 32 + l31) * 128 + (((1 * 2 + hf) * 16) ^ swz));
            bf16x8 K2 = *(const bf16x8*)(base + (kt * 32 + l31) * 128 + (((2 * 2 + hf) * 16) ^ swz));
            bf16x8 K3 = *(const bf16x8*)(base + (kt * 32 + l31) * 128 + (((3 * 2 + hf) * 16) ^ swz));
            __builtin_amdgcn_s_setprio(1);
            f32x16 sA = zero16();
            sA = mfma32(K0, Qf[0], sA); sA = mfma32(K1, Qf[1], sA);
            sA = mfma32(K2, Qf[2], sA); sA = mfma32(K3, Qf[3], sA);
            __builtin_amdgcn_s_setprio(0);
            if (anyzero) {
#pragma unroll
                for (int r = 0; r < 16; ++r) {
                    int kk = k0 + kt * 32 + (r & 3) + 8 * (r >> 2) + 4 * hf;
                    if (maskp[(size_t)n * S_ + kk] == 0) sA[r] = -1e30f;
                }
            }
            float p[16];
#pragma unroll
            for (int r = 0; r < 16; ++r) p[r] = __builtin_amdgcn_exp2f(sA[r]);
            lsum += ((((p[0] + p[1]) + (p[2] + p[3])) + ((p[4] + p[5]) + (p[6] + p[7])))
                  + (((p[8] + p[9]) + (p[10] + p[11])) + ((p[12] + p[13]) + (p[14] + p[15]))));
            u32 w0 = pack2(p[0],  p[1]),  w1 = pack2(p[2],  p[3]);
            u32 w2 = pack2(p[4],  p[5]),  w3 = pack2(p[6],  p[7]);
            u32 w4 = pack2(p[8],  p[9]),  w5 = pack2(p[10], p[11]);
            u32 w6 = pack2(p[12], p[13]), w7 = pack2(p[14], p[15]);
            swap32(w0, w2); swap32(w1, w3); swap32(w4, w6); swap32(w5, w7);
            u32x4 t0; t0[0] = w0; t0[1] = w1; t0[2] = w2; t0[3] = w3;
            u32x4 t1; t1[0] = w4; t1[1] = w5; t1[2] = w6; t1[3] = w7;
            bf16x8 P0 = __builtin_bit_cast(bf16x8, t0);
            bf16x8 P1 = __builtin_bit_cast(bf16x8, t1);
            bf16x8 V00 = *(const bf16x8*)(vbase + (0 * 32 + l31) * 128 + ((((kt * 2 + 0) * 2 + hf) * 16) ^ swz));
            bf16x8 V01 = *(const bf16x8*)(vbase + (0 * 32 + l31) * 128 + ((((kt * 2 + 1) * 2 + hf) * 16) ^ swz));
            bf16x8 V10 = *(const bf16x8*)(vbase + (1 * 32 + l31) * 128 + ((((kt * 2 + 0) * 2 + hf) * 16) ^ swz));
            bf16x8 V11 = *(const bf16x8*)(vbase + (1 * 32 + l31) * 128 + ((((kt * 2 + 1) * 2 + hf) * 16) ^ swz));
            __builtin_amdgcn_s_setprio(1);
            acc0 = mfma32(V00, P0, acc0); acc0 = mfma32(V01, P1, acc0);
            acc1 = mfma32(V10, P0, acc1); acc1 = mfma32(V11, P1, acc1);
            __builtin_amdgcn_s_setprio(0);
        }
        buf ^= 1;
    }

    lsum += __shfl_xor(lsum, 32);
    const float inv = 1.0f / lsum;
    const int qg = q0 + l31;
    __bf16* Ob = Xws + ((size_t)(n * S_ + qg)) * E_ + hd * 64;
    const int qsw = (qg & 7) << 3;

    auto store_half = [&](const f32x16& a, int dv) {
#pragma unroll
        for (int rr = 0; rr < 4; ++rr) {
            bf16x4 o;
#pragma unroll
            for (int j = 0; j < 4; ++j) o[j] = (__bf16)(a[rr * 4 + j] * inv);
            int dsw = ((dv * 32 + rr * 8) ^ qsw) + hf * 4;  // pre-swizzle for k_out
            *(bf16x4*)(Ob + dsw) = o;
        }
    };
    store_half(acc0, 0);
    store_half(acc1, 1);
}

// ------------------------------------------------------- output GEMM + bias
// 128x128 block tile, BK=64, LDS-staged (global_load_lds, double-buffered),
// swizzled ds_read_b128 (swizzle pre-applied in global X / Wob).
__global__ __launch_bounds__(256) void k_out(const __bf16* __restrict__ Xws,
                                             const __bf16* __restrict__ Wob,
                                             const float* __restrict__ bo,
                                             float* __restrict__ out) {
    __shared__ __align__(16) char Al[2][16384];
    __shared__ __align__(16) char Bl[2][16384];
    const int tid = threadIdx.x, lane = tid & 63, wid = tid >> 6;
    const int l31 = lane & 31, hf = lane >> 5;
    const int v = blockIdx.x;
    const int id2 = (v & 7) * 64 + (v >> 3);
    const int mb = id2 >> 3, ob = id2 & 7;
    const int m0 = mb * 128, o0 = ob * 128;
    const int wr = wid >> 1, wc = wid & 1;

    const char* Xb = (const char*)Xws + (size_t)m0 * 2048;
    const char* Wb = (const char*)Wob + (size_t)o0 * 2048;
    const int r = tid >> 3, cb = (tid & 7) * 16;

    auto stage = [&](int buf, int kb) {
#pragma unroll
        for (int p = 0; p < 4; ++p) {
            gload_lds16(Xb + (size_t)(p * 32 + r) * 2048 + kb * 128 + cb,
                        &Al[buf][p * 4096 + wid * 1024]);
            gload_lds16(Wb + (size_t)(p * 32 + r) * 2048 + kb * 128 + cb,
                        &Bl[buf][p * 4096 + wid * 1024]);
        }
    };

    f32x16 acc00 = zero16(), acc01 = zero16(), acc10 = zero16(), acc11 = zero16();

    const int arow0 = (wr * 64 + l31) * 128;
    const int brow0 = (wc * 64 + l31) * 128;
    const int rsw = (l31 & 7) << 4;

    stage(0, 0);
    int buf = 0;
    for (int kb = 0; kb < 16; ++kb) {
        __syncthreads();
        if (kb < 15) stage(buf ^ 1, kb + 1);
        const char* ab = &Al[buf][0];
        const char* bb = &Bl[buf][0];
#pragma unroll
        for (int ks = 0; ks < 4; ++ks) {
            const int co = (ks * 32 + hf * 16) ^ rsw;
            bf16x8 A0 = *(const bf16x8*)(ab + arow0 + co);
            bf16x8 A1 = *(const bf16x8*)(ab + arow0 + 32 * 128 + co);
            bf16x8 B0 = *(const bf16x8*)(bb + brow0 + co);
            bf16x8 B1 = *(const bf16x8*)(bb + brow0 + 32 * 128 + co);
            __builtin_amdgcn_s_setprio(1);
            acc00 = mfma32(A0, B0, acc00);
            acc01 = mfma32(A0, B1, acc01);
            acc10 = mfma32(A1, B0, acc10);
            acc11 = mfma32(A1, B1, acc11);
            __builtin_amdgcn_s_setprio(0);
        }
        buf ^= 1;
    }

    const float bias0 = bo[o0 + wc * 64 + l31];
    const float bias1 = bo[o0 + wc * 64 + 32 + l31];
#pragma unroll
    for (int sm = 0; sm < 2; ++sm) {
        const f32x16& a0 = (sm == 0) ? acc00 : acc10;
        const f32x16& a1 = (sm == 0) ? acc01 : acc11;
#pragma unroll
        for (int rr = 0; rr < 4; ++rr)
#pragma unroll
            for (int j = 0; j < 4; ++j) {
                size_t m = (size_t)m0 + wr * 64 + sm * 32 + rr * 8 + hf * 4 + j;
                out[m * E_ + o0 + wc * 64 + l31]      = a0[rr * 4 + j] + bias0;
                out[m * E_ + o0 + wc * 64 + 32 + l31] = a1[rr * 4 + j] + bias1;
            }
    }
}

extern "C" void kernel_launch(void* const* d_in, const int* in_sizes, int n_in,
                              void* d_out, int out_size, void* d_ws, size_t ws_size,
                              hipStream_t stream) {
    const float* vin  = (const float*)d_in[0];
    const float* kin  = (const float*)d_in[1];
    const float* qin  = (const float*)d_in[2];
    const int*   mask = (const int*)d_in[3];
    const float* Wv   = (const float*)d_in[4];
    const float* Wk   = (const float*)d_in[5];
    const float* Wq   = (const float*)d_in[6];
    const float* Wo   = (const float*)d_in[7];
    const float* bo   = (const float*)d_in[8];

    __bf16* Qws = (__bf16*)d_ws;                       // [64][2048][64]
    __bf16* Kws = Qws + (size_t)NH_ * S_ * 64;         // [64][2048][64] swizzled
    __bf16* Vt  = Kws + (size_t)NH_ * S_ * 64;         // [64][64][2048] swizzled
    __bf16* Xws = Vt  + (size_t)NH_ * S_ * 64;         // [4][2048][1024] swizzled
    __bf16* Wob = Xws + (size_t)4 * S_ * E_;           // [1024][1024] swizzled
    float* out = (float*)d_out;

    hipLaunchKernelGGL(k_proj, dim3(512, 1, 4), dim3(256), 0, stream,
                       vin, kin, qin, Wv, Wk, Wq, Wo, Qws, Kws, Vt, Wob);
    hipLaunchKernelGGL(k_attn, dim3(1024), dim3(256), 0, stream, Qws, Kws, Vt, mask, Xws);
    hipLaunchKernelGGL(k_out, dim3(512), dim3(256), 0, stream, Xws, Wob, bo, out);
}